// Round 6
// baseline (5092.222 us; speedup 1.0000x reference)
//
#include <hip/hip_runtime.h>
#include <cstdint>
#include <cstddef>

// Problem dims (fixed by reference setup_inputs)
#define T_STEPS 1000
#define BATCH   64
#define NI_DIM  700
#define NF_DIM  1024
#define NO_DIM  20
#define M_DIM   (T_STEPS * BATCH)   // 64000

// Workspace layout (float offsets)
#define XW_OFF    0ull                          // [64000][1024] = x @ w_in^T
#define WRT_OFF   (XW_OFF + 65536000ull)        // [1024][1024]  w_rec^T
#define WINT_OFF  (WRT_OFF + 1048576ull)        // [700][1024]   w_in^T
#define WOUTT_OFF (WINT_OFF + 716800ull)        // [1024][20]    w_out^T
#define FLAGS_OFF (WOUTT_OFF + 20480ull)        // 512 ints
#define WS_FLOATS (FLAGS_OFF + 512ull)

// Fused-kernel geometry (512-thread blocks)
#define REC_WGS  64
#define GBM 128
#define GBN 256
#define GBK 16
#define MT_TILES (M_DIM / GBM)      // 500 (1 m-tile = 2 timesteps x 64 batches)
#define NT_TILES (NF_DIM / GBN)     // 4
#define SMEM_BYTES 25088            // max(gemm 25088, rec ~9.7KB)

typedef float vfloat4 __attribute__((ext_vector_type(4)));

// ---------------------------------------------------------------------------
// Tiled transpose: dst[c*R + r] = src[r*C + c]
// ---------------------------------------------------------------------------
__global__ void transpose_k(const float* __restrict__ src, float* __restrict__ dst,
                            int R, int C) {
  __shared__ float tile[32][33];
  int c0 = blockIdx.x * 32, r0 = blockIdx.y * 32;
  int x = threadIdx.x, y = threadIdx.y;  // block (32, 8)
#pragma unroll
  for (int j = 0; j < 32; j += 8) {
    int r = r0 + y + j, c = c0 + x;
    if (r < R && c < C) tile[y + j][x] = src[(size_t)r * C + c];
  }
  __syncthreads();
#pragma unroll
  for (int j = 0; j < 32; j += 8) {
    int r = r0 + x, c = c0 + y + j;
    if (c < C && r < R) dst[(size_t)c * R + r] = tile[x][y + j];
  }
}

__global__ void zero_flags_k(int* __restrict__ flags) {
  if (threadIdx.x < 512) flags[threadIdx.x] = 0;
}

// ---------------------------------------------------------------------------
// Fused kernel (512 threads). Blocks 0..63: recurrence (1 per batch, 2
// neurons/thread). Blocks 64..2063: GEMM tiles of XW = x @ w_in^T,
// publishing per-m-tile flags (agent scope).
// ---------------------------------------------------------------------------
__global__ __launch_bounds__(512, 4) void fused_k(
    const float* __restrict__ x, const float* __restrict__ w_inT,
    float* __restrict__ XW, const float* __restrict__ wrT,
    const float* __restrict__ w_outT, int* __restrict__ flags,
    float* __restrict__ out) {
  __shared__ __attribute__((aligned(16))) char smem[SMEM_BYTES];
  const int tid = threadIdx.x;

  if (blockIdx.x >= REC_WGS) {
    // ------------------------- GEMM producer role -------------------------
    float (*As)[GBM + 4] = reinterpret_cast<float (*)[GBM + 4]>(smem);
    float (*Bs)[GBN + 4] =
        reinterpret_cast<float (*)[GBN + 4]>(smem + GBK * (GBM + 4) * 4);
    const int id = blockIdx.x - REC_WGS;
    const int mt = id >> 2;          // ascending mt with blockIdx
    const int nt = id & 3;
    const int m0 = mt * GBM, n0 = nt * GBN;
    const int tx = tid & 31;         // column group: cols tx + 32*j
    const int ty = tid >> 5;         // row group: rows ty*8 + i

    float acc[8][8];
#pragma unroll
    for (int i = 0; i < 8; ++i)
#pragma unroll
      for (int j = 0; j < 8; ++j) acc[i][j] = 0.f;

    for (int k0 = 0; k0 < NI_DIM; k0 += GBK) {
      {  // A tile: 128 rows x 16 k; 4 scalar nt loads/thread
        int ar = tid >> 2, ac = (tid & 3) * 4;
        const float* src = x + (size_t)(m0 + ar) * NI_DIM + k0 + ac;
#pragma unroll
        for (int u = 0; u < 4; ++u) {
          float vv = (k0 + ac + u < NI_DIM) ? __builtin_nontemporal_load(src + u) : 0.f;
          As[ac + u][ar] = vv;
        }
      }
      {  // B tile: 16 k-rows x 256 cols; 2 float4 per thread
        int r = tid >> 5, c8 = (tid & 31) * 8;
        int kk = k0 + r;
        float4 v0 = make_float4(0.f, 0.f, 0.f, 0.f);
        float4 v1 = make_float4(0.f, 0.f, 0.f, 0.f);
        if (kk < NI_DIM) {
          const float* bp = w_inT + (size_t)kk * NF_DIM + n0 + c8;
          v0 = *reinterpret_cast<const float4*>(bp);
          v1 = *reinterpret_cast<const float4*>(bp + 4);
        }
        *reinterpret_cast<float4*>(&Bs[r][c8]) = v0;
        *reinterpret_cast<float4*>(&Bs[r][c8 + 4]) = v1;
      }
      __syncthreads();
#pragma unroll
      for (int k = 0; k < GBK; ++k) {
        float a[8], b[8];
#pragma unroll
        for (int i = 0; i < 8; ++i) a[i] = As[k][ty * 8 + i];
#pragma unroll
        for (int j = 0; j < 8; ++j) b[j] = Bs[k][tx + 32 * j];  // lane-consecutive: no conflict
#pragma unroll
        for (int i = 0; i < 8; ++i)
#pragma unroll
          for (int j = 0; j < 8; ++j) acc[i][j] += a[i] * b[j];
      }
      __syncthreads();
    }

#pragma unroll
    for (int i = 0; i < 8; ++i) {
      size_t row = (size_t)(m0 + ty * 8 + i);
      float* cp = XW + row * NF_DIM + n0 + tx;
#pragma unroll
      for (int j = 0; j < 8; ++j)
        __builtin_nontemporal_store(acc[i][j], cp + 32 * j);  // lanes coalesced
    }
    __syncthreads();  // drains vmcnt -> stores complete
    if (tid == 0)
      __hip_atomic_fetch_add(&flags[mt], 1, __ATOMIC_RELEASE,
                             __HIP_MEMORY_SCOPE_AGENT);
    return;
  }

  // ------------------- recurrence consumer role (2 neurons/thread) -------------------
  {
#pragma clang fp contract(off)
    int*   s_flat = reinterpret_cast<int*>(smem);           // [2][1024]
    int*   s_wcnt = reinterpret_cast<int*>(smem + 8192);    // [2][16]
    float* s_part = reinterpret_cast<float*>(smem + 8320);  // [2][8][20]
    float* s_vo   = reinterpret_cast<float*>(smem + 9600);  // [20]

    const int b = blockIdx.x;
    const int lane = tid & 63, wid = tid >> 6;   // wid 0..7
    const unsigned n0u = (unsigned)tid;          // neuron A
    const unsigned n1u = (unsigned)tid + 512;    // neuron B

    float v0 = 0.f, cur0 = 0.f;   // neuron A state
    float v1 = 0.f, cur1 = 0.f;   // neuron B state
    float vo = 0.f, io = 0.f;     // readout state (threads 0..19)
    int C = 0;                    // previous step's spike count

    const float* xwp = XW + (size_t)b * NF_DIM + tid;

    if (tid == 0) {  // chunk 0 covers t=0,1
      while (__hip_atomic_load(&flags[0], __ATOMIC_RELAXED,
                               __HIP_MEMORY_SCOPE_AGENT) < NT_TILES)
        __builtin_amdgcn_s_sleep(2);
      (void)__hip_atomic_load(&flags[0], __ATOMIC_ACQUIRE,
                              __HIP_MEMORY_SCOPE_AGENT);
    }
    __syncthreads();

    for (int t = 0; t < T_STEPS; ++t) {
      const int pn = t & 1, po = pn ^ 1;
      const float* xt = xwp + (size_t)t * (BATCH * NF_DIM);
      float xwv0 = __builtin_nontemporal_load(xt);
      float xwv1 = __builtin_nontemporal_load(xt + 512);

      // ---- recurrent gather, ascending neuron order (bitwise == R3/R5) ----
      const int* fl = s_flat + po * NF_DIM;
      float recA = 0.f, recB = 0.f;
      int kk = 0;
      for (; kk + 32 <= C; kk += 32) {
        int idx[32];
#pragma unroll
        for (int u = 0; u < 8; ++u)
          *reinterpret_cast<int4*>(&idx[u * 4]) =
              *reinterpret_cast<const int4*>(&fl[kk + u * 4]);
        float valA[32], valB[32];
#pragma unroll
        for (int u = 0; u < 32; ++u) {
          const float* rp = wrT + (((unsigned)idx[u]) << 10);
          valA[u] = rp[n0u];
          valB[u] = rp[n1u];
        }
#pragma unroll
        for (int u = 0; u < 32; ++u) recA += valA[u];  // sequential: order kept
#pragma unroll
        for (int u = 0; u < 32; ++u) recB += valB[u];
      }
      for (; kk + 8 <= C; kk += 8) {
        int idx[8];
#pragma unroll
        for (int u = 0; u < 2; ++u)
          *reinterpret_cast<int4*>(&idx[u * 4]) =
              *reinterpret_cast<const int4*>(&fl[kk + u * 4]);
        float valA[8], valB[8];
#pragma unroll
        for (int u = 0; u < 8; ++u) {
          const float* rp = wrT + (((unsigned)idx[u]) << 10);
          valA[u] = rp[n0u];
          valB[u] = rp[n1u];
        }
#pragma unroll
        for (int u = 0; u < 8; ++u) recA += valA[u];
#pragma unroll
        for (int u = 0; u < 8; ++u) recB += valB[u];
      }
      for (; kk < C; ++kk) {
        const float* rp = wrT + (((unsigned)fl[kk]) << 10);
        recA += rp[n0u];
        recB += rp[n1u];
      }

      // ---- LIF update x2 (no fma contraction; bitwise == prior rounds) ----
      float i_dec0 = cur0 * 0.8f;
      float v_dec0 = v0 + 0.1f * (cur0 - v0);
      bool  z0     = v_dec0 > 1.0f;
      v0   = z0 ? 0.f : v_dec0;
      cur0 = (i_dec0 + xwv0) + recA;

      float i_dec1 = cur1 * 0.8f;
      float v_dec1 = v1 + 0.1f * (cur1 - v1);
      bool  z1     = v_dec1 > 1.0f;
      v1   = z1 ? 0.f : v_dec1;
      cur1 = (i_dec1 + xwv1) + recB;

      // ---- publish spikes: wave w owns segments w (low half) and w+8 ----
      unsigned long long m0 = __ballot(z0);
      unsigned long long m1 = __ballot(z1);
      unsigned long long ltmask = (1ull << lane) - 1ull;
      int pos0 = __popcll(m0 & ltmask);
      int pos1 = __popcll(m1 & ltmask);
      if (lane == 0) {
        s_wcnt[pn * 16 + wid]     = __popcll(m0);
        s_wcnt[pn * 16 + 8 + wid] = __popcll(m1);
      }

      // per-wave readout partials over both segments (feed-forward; reassoc safe)
      if (lane < NO_DIM) {
        float p = 0.f;
        unsigned long long mm = m0;
        while (mm) {
          int bset = __builtin_ctzll(mm);
          mm &= mm - 1;
          p += w_outT[((wid << 6) + bset) * NO_DIM + lane];
        }
        mm = m1;
        while (mm) {
          int bset = __builtin_ctzll(mm);
          mm &= mm - 1;
          p += w_outT[((512 + (wid << 6)) + bset) * NO_DIM + lane];
        }
        s_part[(pn * 8 + wid) * NO_DIM + lane] = p;
      }

      __syncthreads();  // #1: wcnt + partials ready

      int total = 0, off0 = 0, off1 = 0;
#pragma unroll
      for (int s = 0; s < 16; ++s) {
        int c = s_wcnt[pn * 16 + s];
        if (s < wid)     off0 += c;
        if (s < 8 + wid) off1 += c;
        total += c;
      }
      if (z0) s_flat[pn * NF_DIM + off0 + pos0] = tid;
      if (z1) s_flat[pn * NF_DIM + off1 + pos1] = tid + 512;
      C = total;

      if (tid < NO_DIM) {
        float io_dec = io * 0.8f;
        vo = vo + 0.1f * (io - vo);
        float acc = 0.f;
#pragma unroll
        for (int w = 0; w < 8; ++w) acc += s_part[(pn * 8 + w) * NO_DIM + tid];
        io = io_dec + acc;
      }

      // piggyback next chunk's flag wait on barrier #2 (thread 0 only)
      if ((t & 1) && (t + 1 < T_STEPS) && tid == 0) {
        const int c = (t + 1) >> 1;
        while (__hip_atomic_load(&flags[c], __ATOMIC_RELAXED,
                                 __HIP_MEMORY_SCOPE_AGENT) < NT_TILES)
          __builtin_amdgcn_s_sleep(2);
        (void)__hip_atomic_load(&flags[c], __ATOMIC_ACQUIRE,
                                __HIP_MEMORY_SCOPE_AGENT);
      }
      __syncthreads();  // #2: flat list complete (and next XW chunk visible)
    }

    // log_softmax over NO=20 per batch
    if (tid < NO_DIM) s_vo[tid] = vo;
    __syncthreads();
    if (tid < NO_DIM) {
      float mx = -3.402823466e+38f;
      for (int j = 0; j < NO_DIM; ++j) mx = fmaxf(mx, s_vo[j]);
      float sum = 0.f;
      for (int j = 0; j < NO_DIM; ++j) sum += expf(s_vo[j] - mx);
      out[(size_t)b * NO_DIM + tid] = (vo - mx) - logf(sum);
    }
  }
}

// ---------------------------------------------------------------------------
extern "C" void kernel_launch(void* const* d_in, const int* in_sizes, int n_in,
                              void* d_out, int out_size, void* d_ws, size_t ws_size,
                              hipStream_t stream) {
  const float* x     = (const float*)d_in[0];
  const float* w_in  = (const float*)d_in[1];
  const float* w_rec = (const float*)d_in[2];
  const float* w_out = (const float*)d_in[3];
  float* out = (float*)d_out;
  float* ws  = (float*)d_ws;

  if (ws_size < WS_FLOATS * sizeof(float)) return;

  float* xw    = ws + XW_OFF;
  float* wrT   = ws + WRT_OFF;
  float* w_inT = ws + WINT_OFF;
  float* w_oT  = ws + WOUTT_OFF;
  int*   flags = (int*)(ws + FLAGS_OFF);

  // transposes + flag reset (dispatch-boundary flush makes them visible)
  {
    dim3 blk(32, 8);
    dim3 g1((NI_DIM + 31) / 32, (NF_DIM + 31) / 32);
    transpose_k<<<g1, blk, 0, stream>>>(w_in, w_inT, NF_DIM, NI_DIM);
    dim3 g2((NF_DIM + 31) / 32, (NF_DIM + 31) / 32);
    transpose_k<<<g2, blk, 0, stream>>>(w_rec, wrT, NF_DIM, NF_DIM);
    dim3 g3((NF_DIM + 31) / 32, (NO_DIM + 31) / 32);
    transpose_k<<<g3, blk, 0, stream>>>(w_out, w_oT, NO_DIM, NF_DIM);
    zero_flags_k<<<1, 512, 0, stream>>>(flags);
  }

  // fused producer-consumer: recurrence WGs first (resident from t=0)
  fused_k<<<REC_WGS + MT_TILES * NT_TILES, 512, 0, stream>>>(
      x, w_inT, xw, wrT, w_oT, flags, out);
}

// Round 7
// 3386.227 us; speedup vs baseline: 1.5038x; 1.5038x over previous
//
#include <hip/hip_runtime.h>
#include <cstdint>
#include <cstddef>

// Problem dims (fixed by reference setup_inputs)
#define T_STEPS 1000
#define BATCH   64
#define NI_DIM  700
#define NF_DIM  1024
#define NO_DIM  20
#define M_DIM   (T_STEPS * BATCH)   // 64000

// Workspace layout (float offsets)
#define XW_OFF    0ull                          // [64000][1024] = x @ w_in^T
#define WRT_OFF   (XW_OFF + 65536000ull)        // [1024][1024]  w_rec^T
#define WINT_OFF  (WRT_OFF + 1048576ull)        // [700][1024]   w_in^T
#define WOUTT_OFF (WINT_OFF + 716800ull)        // [1024][20]    w_out^T
#define FLAGS_OFF (WOUTT_OFF + 20480ull)        // 512 ints
#define WS_FLOATS (FLAGS_OFF + 512ull)

// Fused-kernel geometry (1024-thread blocks, as in R5)
#define REC_WGS  64
#define GBM 128
#define GBN 256
#define GBK 16
#define MT_TILES (M_DIM / GBM)      // 500 (1 m-tile = 2 timesteps x 64 batches)
#define NT_TILES (NF_DIM / GBN)     // 4
#define SMEM_BYTES 25088            // max(gemm 25088, rec 10960)

// ---------------------------------------------------------------------------
// Tiled transpose: dst[c*R + r] = src[r*C + c]
// ---------------------------------------------------------------------------
__global__ void transpose_k(const float* __restrict__ src, float* __restrict__ dst,
                            int R, int C) {
  __shared__ float tile[32][33];
  int c0 = blockIdx.x * 32, r0 = blockIdx.y * 32;
  int x = threadIdx.x, y = threadIdx.y;  // block (32, 8)
#pragma unroll
  for (int j = 0; j < 32; j += 8) {
    int r = r0 + y + j, c = c0 + x;
    if (r < R && c < C) tile[y + j][x] = src[(size_t)r * C + c];
  }
  __syncthreads();
#pragma unroll
  for (int j = 0; j < 32; j += 8) {
    int r = r0 + x, c = c0 + y + j;
    if (c < C && r < R) dst[(size_t)c * R + r] = tile[x][y + j];
  }
}

__global__ void zero_flags_k(int* __restrict__ flags) {
  if (threadIdx.x < 512) flags[threadIdx.x] = 0;
}

// ---------------------------------------------------------------------------
// Fused kernel (1024 threads). Blocks 0..63: recurrence (1 per batch).
// Blocks 64..2063: GEMM tiles of XW = x @ w_in^T, per-m-tile release flags.
// ---------------------------------------------------------------------------
__global__ __launch_bounds__(1024, 4) void fused_k(
    const float* __restrict__ x, const float* __restrict__ w_inT,
    float* __restrict__ XW, const float* __restrict__ wrT,
    const float* __restrict__ w_outT, int* __restrict__ flags,
    float* __restrict__ out) {
  __shared__ __attribute__((aligned(16))) char smem[SMEM_BYTES];
  const int tid = threadIdx.x;

  if (blockIdx.x >= REC_WGS) {
    // ------------------------- GEMM producer role -------------------------
    float (*As)[GBM + 4] = reinterpret_cast<float (*)[GBM + 4]>(smem);
    float (*Bs)[GBN + 4] =
        reinterpret_cast<float (*)[GBN + 4]>(smem + GBK * (GBM + 4) * 4);
    const int id = blockIdx.x - REC_WGS;
    const int mt = id >> 2;          // ascending mt with blockIdx
    const int nt = id & 3;
    const int m0 = mt * GBM, n0 = nt * GBN;
    const int tx = tid & 31;         // column: cols n0 + tx + 32*j (lane-consecutive)
    const int ty = tid >> 5;         // rows ty*4 + i

    float acc[4][8];
#pragma unroll
    for (int i = 0; i < 4; ++i)
#pragma unroll
      for (int j = 0; j < 8; ++j) acc[i][j] = 0.f;

    for (int k0 = 0; k0 < NI_DIM; k0 += GBK) {
      {  // A tile: 128 rows x 16 k (2 elems/thread), nt loads
        int ar = tid >> 3, ac = (tid & 7) * 2;
        const float* src = x + (size_t)(m0 + ar) * NI_DIM + k0 + ac;
        float v0 = (k0 + ac     < NI_DIM) ? __builtin_nontemporal_load(src)     : 0.f;
        float v1 = (k0 + ac + 1 < NI_DIM) ? __builtin_nontemporal_load(src + 1) : 0.f;
        As[ac][ar] = v0;
        As[ac + 1][ar] = v1;
      }
      {  // B tile: 16 k-rows x 256 cols (float4/thread)
        int r = tid >> 6, c4 = (tid & 63) * 4;
        int kk = k0 + r;
        float4 vv = make_float4(0.f, 0.f, 0.f, 0.f);
        if (kk < NI_DIM)
          vv = *reinterpret_cast<const float4*>(w_inT + (size_t)kk * NF_DIM + n0 + c4);
        *reinterpret_cast<float4*>(&Bs[r][c4]) = vv;
      }
      __syncthreads();
#pragma unroll
      for (int k = 0; k < GBK; ++k) {
        float a[4], b[8];
#pragma unroll
        for (int i = 0; i < 4; ++i) a[i] = As[k][ty * 4 + i];
#pragma unroll
        for (int j = 0; j < 8; ++j) b[j] = Bs[k][tx + 32 * j];  // stride-1 lanes: conflict-free
#pragma unroll
        for (int i = 0; i < 4; ++i)
#pragma unroll
          for (int j = 0; j < 8; ++j) acc[i][j] += a[i] * b[j];
      }
      __syncthreads();
    }

#pragma unroll
    for (int i = 0; i < 4; ++i) {
      size_t row = (size_t)(m0 + ty * 4 + i);
      float* cp = XW + row * NF_DIM + n0 + tx;
#pragma unroll
      for (int j = 0; j < 8; ++j)
        __builtin_nontemporal_store(acc[i][j], cp + 32 * j);  // lanes coalesced (128B/half-wave)
    }
    __syncthreads();  // drains vmcnt -> stores complete
    if (tid == 0)
      __hip_atomic_fetch_add(&flags[mt], 1, __ATOMIC_RELEASE,
                             __HIP_MEMORY_SCOPE_AGENT);
    return;
  }

  // ------------------------- recurrence consumer role (== R5) -------------------------
  {
#pragma clang fp contract(off)
    int*   s_flat = reinterpret_cast<int*>(smem);           // [2][1024]
    int*   s_wcnt = reinterpret_cast<int*>(smem + 8192);    // [2][16]
    float* s_part = reinterpret_cast<float*>(smem + 8320);  // [2][16][20]
    float* s_vo   = reinterpret_cast<float*>(smem + 10880); // [20]

    const int b = blockIdx.x;
    const int lane = tid & 63, wid = tid >> 6;
    const unsigned tidu = (unsigned)tid;

    float v = 0.f, cur = 0.f;   // membrane, synaptic current
    float vo = 0.f, io = 0.f;   // readout state (threads 0..19)
    int C = 0;                  // previous step's spike count

    const float* xwp = XW + (size_t)b * NF_DIM + tid;

    if (tid == 0) {  // chunk 0 covers t=0,1
      while (__hip_atomic_load(&flags[0], __ATOMIC_RELAXED,
                               __HIP_MEMORY_SCOPE_AGENT) < NT_TILES)
        __builtin_amdgcn_s_sleep(2);
      (void)__hip_atomic_load(&flags[0], __ATOMIC_ACQUIRE,
                              __HIP_MEMORY_SCOPE_AGENT);
    }
    __syncthreads();

    for (int t = 0; t < T_STEPS; ++t) {
      const int pn = t & 1, po = pn ^ 1;
      float xwv = __builtin_nontemporal_load(xwp + (size_t)t * (BATCH * NF_DIM));

      // ---- recurrent gather, ascending neuron order (bitwise == R3/R5) ----
      const int* fl = s_flat + po * NF_DIM;
      float rec = 0.f;
      int kk = 0;
      for (; kk + 32 <= C; kk += 32) {
        int idx[32];
#pragma unroll
        for (int u = 0; u < 8; ++u)
          *reinterpret_cast<int4*>(&idx[u * 4]) =
              *reinterpret_cast<const int4*>(&fl[kk + u * 4]);
        float val[32];
#pragma unroll
        for (int u = 0; u < 32; ++u)
          val[u] = wrT[(((unsigned)idx[u]) << 10) + tidu];
#pragma unroll
        for (int u = 0; u < 32; ++u) rec += val[u];  // sequential: order kept
      }
      for (; kk + 8 <= C; kk += 8) {
        int idx[8];
#pragma unroll
        for (int u = 0; u < 2; ++u)
          *reinterpret_cast<int4*>(&idx[u * 4]) =
              *reinterpret_cast<const int4*>(&fl[kk + u * 4]);
        float val[8];
#pragma unroll
        for (int u = 0; u < 8; ++u)
          val[u] = wrT[(((unsigned)idx[u]) << 10) + tidu];
#pragma unroll
        for (int u = 0; u < 8; ++u) rec += val[u];
      }
      for (; kk < C; ++kk) rec += wrT[(((unsigned)fl[kk]) << 10) + tidu];

      // ---- LIF update (no fma contraction; bitwise == prior rounds) ----
      float i_dec = cur * 0.8f;
      float v_dec = v + 0.1f * (cur - v);
      bool  z     = v_dec > 1.0f;
      v   = z ? 0.f : v_dec;
      cur = (i_dec + xwv) + rec;

      // ---- publish spikes ----
      unsigned long long m = __ballot(z);
      int pos = __popcll(m & ((1ull << lane) - 1ull));
      if (lane == 0) s_wcnt[pn * 16 + wid] = __popcll(m);

      // per-wave readout partials (feed-forward; reassociation safe)
      if (lane < NO_DIM) {
        float p = 0.f;
        unsigned long long mm = m;
        while (mm) {
          int bset = __builtin_ctzll(mm);
          mm &= mm - 1;
          p += w_outT[((wid << 6) + bset) * NO_DIM + lane];
        }
        s_part[(pn * 16 + wid) * NO_DIM + lane] = p;
      }

      __syncthreads();  // #1: wcnt + partials ready

      int total = 0, myoff = 0;
#pragma unroll
      for (int w = 0; w < 16; ++w) {
        int c = s_wcnt[pn * 16 + w];
        if (w < wid) myoff += c;
        total += c;
      }
      if (z) s_flat[pn * NF_DIM + myoff + pos] = tid;
      C = total;

      if (tid < NO_DIM) {
        float io_dec = io * 0.8f;
        vo = vo + 0.1f * (io - vo);
        float acc = 0.f;
#pragma unroll
        for (int w = 0; w < 16; ++w) acc += s_part[(pn * 16 + w) * NO_DIM + tid];
        io = io_dec + acc;
      }

      // piggyback next chunk's flag wait on barrier #2 (thread 0 only)
      if ((t & 1) && (t + 1 < T_STEPS) && tid == 0) {
        const int c = (t + 1) >> 1;
        while (__hip_atomic_load(&flags[c], __ATOMIC_RELAXED,
                                 __HIP_MEMORY_SCOPE_AGENT) < NT_TILES)
          __builtin_amdgcn_s_sleep(2);
        (void)__hip_atomic_load(&flags[c], __ATOMIC_ACQUIRE,
                                __HIP_MEMORY_SCOPE_AGENT);
      }
      __syncthreads();  // #2: flat list complete (and next XW chunk visible)
    }

    // log_softmax over NO=20 per batch
    if (tid < NO_DIM) s_vo[tid] = vo;
    __syncthreads();
    if (tid < NO_DIM) {
      float mx = -3.402823466e+38f;
      for (int j = 0; j < NO_DIM; ++j) mx = fmaxf(mx, s_vo[j]);
      float sum = 0.f;
      for (int j = 0; j < NO_DIM; ++j) sum += expf(s_vo[j] - mx);
      out[(size_t)b * NO_DIM + tid] = (vo - mx) - logf(sum);
    }
  }
}

// ---------------------------------------------------------------------------
extern "C" void kernel_launch(void* const* d_in, const int* in_sizes, int n_in,
                              void* d_out, int out_size, void* d_ws, size_t ws_size,
                              hipStream_t stream) {
  const float* x     = (const float*)d_in[0];
  const float* w_in  = (const float*)d_in[1];
  const float* w_rec = (const float*)d_in[2];
  const float* w_out = (const float*)d_in[3];
  float* out = (float*)d_out;
  float* ws  = (float*)d_ws;

  if (ws_size < WS_FLOATS * sizeof(float)) return;

  float* xw    = ws + XW_OFF;
  float* wrT   = ws + WRT_OFF;
  float* w_inT = ws + WINT_OFF;
  float* w_oT  = ws + WOUTT_OFF;
  int*   flags = (int*)(ws + FLAGS_OFF);

  // transposes + flag reset (dispatch-boundary flush makes them visible)
  {
    dim3 blk(32, 8);
    dim3 g1((NI_DIM + 31) / 32, (NF_DIM + 31) / 32);
    transpose_k<<<g1, blk, 0, stream>>>(w_in, w_inT, NF_DIM, NI_DIM);
    dim3 g2((NF_DIM + 31) / 32, (NF_DIM + 31) / 32);
    transpose_k<<<g2, blk, 0, stream>>>(w_rec, wrT, NF_DIM, NF_DIM);
    dim3 g3((NF_DIM + 31) / 32, (NO_DIM + 31) / 32);
    transpose_k<<<g3, blk, 0, stream>>>(w_out, w_oT, NO_DIM, NF_DIM);
    zero_flags_k<<<1, 512, 0, stream>>>(flags);
  }

  // fused producer-consumer: recurrence WGs first (resident from t=0)
  fused_k<<<REC_WGS + MT_TILES * NT_TILES, 1024, 0, stream>>>(
      x, w_inT, xw, wrT, w_oT, flags, out);
}